// Round 7
// baseline (445.684 us; speedup 1.0000x reference)
//
#include <hip/hip_runtime.h>

#define B_ 1024
#define T_ 200
#define H_ 128
#define TSTR (T_ + 4)  // histbf padded time-stride (pad absorbs prefetch overrun)

typedef __attribute__((ext_vector_type(8))) short short8;
typedef __attribute__((ext_vector_type(4))) float f32x4;

#define MFMA(a, b, c) __builtin_amdgcn_mfma_f32_16x16x32_bf16((a), (b), (c), 0, 0, 0)

static __device__ __forceinline__ short f2bf(float f) {
  unsigned u = __float_as_uint(f);
  u += 0x7fffu + ((u >> 16) & 1u);  // RNE
  return (short)(u >> 16);
}
static __device__ __forceinline__ float bf2f(short s) {
  return __uint_as_float(((unsigned)(unsigned short)s) << 16);
}
// pack two floats as bf16 (RNE) into one dword: low short = a, high short = b
static __device__ __forceinline__ unsigned pack2bf_rne(float a, float b) {
  unsigned ua = __float_as_uint(a);
  ua += 0x7fffu + ((ua >> 16) & 1u);
  unsigned ub = __float_as_uint(b);
  ub += 0x7fffu + ((ub >> 16) & 1u);
  return (ua >> 16) | (ub & 0xFFFF0000u);
}
// truncating pack via one v_perm_b32: dst = [b.hi16 | a.hi16]
static __device__ __forceinline__ unsigned pack2bf_trunc(float a, float b) {
  return __builtin_amdgcn_perm(__float_as_uint(b), __float_as_uint(a), 0x07060302u);
}
static __device__ __forceinline__ float rcp_f(float x) { return __builtin_amdgcn_rcpf(x); }
static __device__ __forceinline__ float exp2_f(float x) { return __builtin_amdgcn_exp2f(x); }
// CK-style barrier: LDS-only drain, does NOT drain vmcnt (keeps global prefetch alive)
static __device__ __forceinline__ void ck_barrier() {
  asm volatile("s_waitcnt lgkmcnt(0)\n\ts_barrier" ::: "memory");
}

// ---------------------------------------------------------------------------
// K_A: attention scores (split bf16 3-pass, fp32-grade) + hist->bf16 repack.
// v3: histbf written DIRECTLY from the prefetched hv registers (no LDS
// re-read, no separate conversion mapping). Thread (sm,cs)'s 4 floats are
// hist[row sm][4cs..4cs+3], which map to histbf slot ks=cs>>3,
// wl = sm + 16*((cs&7)>>1), half = cs&1  (k = 32ks + 8(wl>>4) + 4half = 4cs).
// ---------------------------------------------------------------------------
__global__ __launch_bounds__(512, 1) void proj_scores_kernel(
    const float* __restrict__ tgt, const float* __restrict__ hist,
    const float* __restrict__ Ww, const float* __restrict__ Wb,
    float* __restrict__ scores, short* __restrict__ histbf) {
  const int tc = blockIdx.x, bb = blockIdx.y;
  const int nt = (tc == 12) ? 8 : 16;
  const int t0 = tc * 16;
  const int tid = threadIdx.x;
  const int lane = tid & 63, w = tid >> 6;
  const int n = lane & 15, q = lane >> 4;

  __shared__ short tgt_hi[2][16 * 128];
  __shared__ short tgt_lo[2][16 * 128];
  __shared__ float hist_f[2][16 * 132];  // padded rows
  __shared__ float sp[2][16 * 8];

  // register A-frags for Ww (hi/lo split): A[i][k] = Ww[w*16+i][k]
  short8 whi[4], wlo[4];
  f32x4 wb4;
  {
    const int o = w * 16 + n;
#pragma unroll
    for (int ks = 0; ks < 4; ++ks) {
      const float* p = Ww + o * H_ + ks * 32 + q * 8;
      short8 h, l;
#pragma unroll
      for (int j = 0; j < 8; ++j) {
        float f = p[j];
        short hv = f2bf(f);
        h[j] = hv;
        l[j] = f2bf(f - bf2f(hv));
      }
      whi[ks] = h;
      wlo[ks] = l;
    }
    wb4 = *(const f32x4*)(Wb + w * 16 + q * 4);  // biases for this lane's 4 cols
  }

  // staging: thread -> (row sm, 4-float granule cs)
  const int sm = tid >> 5, cs = tid & 31;
  const int g = cs >> 1, half = cs & 1;
  const int spos16 = sm * 128 + ((g ^ (sm & 7)) * 8) + half * 4;  // shorts
  const int sposf = sm * 132 + cs * 4;                            // floats
  const size_t rowbase = ((size_t)(bb * 16 + sm) * T_) * H_ + cs * 4;

  // direct histbf write slot for this thread (tile t -> hb + (t-t0)*2048)
  const size_t hb = (((size_t)(bb * TSTR + t0) * 4) + (cs >> 3)) * 512 +
                    (sm + ((cs & 7) >> 1) * 16) * 8 + (cs & 1) * 4;

  float4 hv = *(const float4*)(hist + rowbase + (size_t)t0 * H_);
  float4 tv = *(const float4*)(tgt + rowbase + (size_t)t0 * H_);
  {
    *(float4*)&hist_f[0][sposf] = hv;
    uint2 hi, lo;
    hi.x = pack2bf_rne(tv.x, tv.y);
    hi.y = pack2bf_rne(tv.z, tv.w);
    lo.x = pack2bf_rne(tv.x - bf2f((short)(hi.x)), tv.y - bf2f((short)(hi.x >> 16)));
    lo.y = pack2bf_rne(tv.z - bf2f((short)(hi.y)), tv.w - bf2f((short)(hi.y >> 16)));
    *(uint2*)&tgt_hi[0][spos16] = hi;
    *(uint2*)&tgt_lo[0][spos16] = lo;
    if (histbf != nullptr) {  // tile t0 from registers
      uint2 u;
      u.x = pack2bf_rne(hv.x, hv.y);
      u.y = pack2bf_rne(hv.z, hv.w);
      *(uint2*)(histbf + hb) = u;
    }
  }
  ck_barrier();

  for (int tl = 0; tl < nt; ++tl) {
    const int cur = tl & 1, nxt = cur ^ 1;
    const bool have_next = (tl + 1 < nt);
    if (have_next) {
      hv = *(const float4*)(hist + rowbase + (size_t)(t0 + tl + 1) * H_);
      tv = *(const float4*)(tgt + rowbase + (size_t)(t0 + tl + 1) * H_);
      if (histbf != nullptr) {  // tile t0+tl+1 straight from registers
        uint2 u;
        u.x = pack2bf_rne(hv.x, hv.y);
        u.y = pack2bf_rne(hv.z, hv.w);
        *(uint2*)(histbf + hb + (size_t)(tl + 1) * 2048) = u;
      }
    }
    // scores MFMA: 3-pass split bf16, swapped operands (A = W, B = tgt)
    f32x4 s1 = {0, 0, 0, 0}, s2 = {0, 0, 0, 0}, s3 = {0, 0, 0, 0};
#pragma unroll
    for (int ks = 0; ks < 4; ++ks) {
      const int fp = n * 128 + ((ks * 4 + q) ^ (n & 7)) * 8;
      short8 ahi = *(short8*)&tgt_hi[cur][fp];
      short8 alo = *(short8*)&tgt_lo[cur][fp];
      s1 = MFMA(whi[ks], ahi, s1);
      s2 = MFMA(wlo[ks], ahi, s2);
      s3 = MFMA(whi[ks], alo, s3);
    }
    // dot with hist (fp32): lane holds (row n, cols w*16+q*4..+3)
    {
      f32x4 hv4 = *(const f32x4*)&hist_f[cur][n * 132 + w * 16 + q * 4];
      float v = (s1[0] + s2[0] + s3[0] + wb4[0]) * hv4[0];
      v += (s1[1] + s2[1] + s3[1] + wb4[1]) * hv4[1];
      v += (s1[2] + s2[2] + s3[2] + wb4[2]) * hv4[2];
      v += (s1[3] + s2[3] + s3[3] + wb4[3]) * hv4[3];
      v += __shfl_xor(v, 16);
      v += __shfl_xor(v, 32);
      if (lane < 16) sp[cur][n * 8 + w] = v;
    }
    // stage next tile (prefetched regs)
    if (have_next) {
      *(float4*)&hist_f[nxt][sposf] = hv;
      uint2 hi, lo;
      hi.x = pack2bf_rne(tv.x, tv.y);
      hi.y = pack2bf_rne(tv.z, tv.w);
      lo.x = pack2bf_rne(tv.x - bf2f((short)(hi.x)), tv.y - bf2f((short)(hi.x >> 16)));
      lo.y = pack2bf_rne(tv.z - bf2f((short)(hi.y)), tv.w - bf2f((short)(hi.y >> 16)));
      *(uint2*)&tgt_hi[nxt][spos16] = hi;
      *(uint2*)&tgt_lo[nxt][spos16] = lo;
    }
    ck_barrier();
    // finish scores for THIS iter (reads sp[cur]; next iter writes sp[nxt])
    if (tid < 16) {
      float s = 0.0f;
#pragma unroll
      for (int ww = 0; ww < 8; ++ww) s += sp[cur][tid * 8 + ww];
      scores[(size_t)(bb * 16 + tid) * T_ + (t0 + tl)] = s;
    }
  }
}

// ---------------------------------------------------------------------------
// K_C: recurrent scan v10. Model (R2-R6, holds to 2%): step = MFMA + VALU +
// sync, strictly additive (MFMA/VALU share SIMD issue).
// v10: FINAL LAYER FUSED as epilogue (separate kernel + hfin round-trip
// removed): h(T-1) staged fp32 to LDS (reusing att buffer), then each thread
// computes 4 outputs of out = [h | tgt0] @ ln2_w^T + b with k-sliced fp32
// dots (w k-slice = 4KB -> L1-resident per iteration sweep).
// ---------------------------------------------------------------------------
template <bool DIRECT>
__global__ __launch_bounds__(512, 1) void scan3_kernel(
    const float* __restrict__ hist, const float* __restrict__ tgt,
    const float* __restrict__ xu_w, const float* __restrict__ xu_b,
    const float* __restrict__ hu_w, const float* __restrict__ hu_b,
    const float* __restrict__ xr_w, const float* __restrict__ xr_b,
    const float* __restrict__ hr_w, const float* __restrict__ hr_b,
    const float* __restrict__ xg_w, const float* __restrict__ xg_b,
    const float* __restrict__ hg_w, const float* __restrict__ hg_b,
    const float* __restrict__ att_g, const short* __restrict__ histbf,
    const float* __restrict__ ln2_w, const float* __restrict__ ln2_b,
    float* __restrict__ out) {
  const int tid = threadIdx.x;
  const int lane = tid & 63, w = tid >> 6;
  const int n = lane & 15, q = lane >> 4;
  const int bb = blockIdx.x, r0 = bb * 16;
  const int o = w * 16 + n;       // A-frag packing index (W rows = output cols)
  const int ob = w * 16 + q * 4;  // this lane's 4 output cols (D layout)

  constexpr float LOG2E = 1.4426950408889634f;

  __shared__ short hbuf[2][16 * 128];
  __shared__ short xbuf[2][16 * 128];  // only used when !DIRECT (else dead)
  __shared__ float att_lds[16 * 204];  // softmax result; reused for h in epilogue

  // A-frags: 0=xu 1=hu 2=xr 3=hr 4=xg 5=hg  (96 VGPRs)
  // exp2-prescaled: u/r rows by log2e, g rows by 2*log2e.
  short8 wf[6][4];
  {
    const float* Wm[6] = {xu_w, hu_w, xr_w, hr_w, xg_w, hg_w};
    const float Sc[6] = {LOG2E, LOG2E, LOG2E, LOG2E, 2.0f * LOG2E, 2.0f * LOG2E};
#pragma unroll
    for (int M = 0; M < 6; ++M)
#pragma unroll
      for (int ks = 0; ks < 4; ++ks) {
        const float* p = Wm[M] + o * H_ + ks * 32 + q * 8;
        short8 v;
#pragma unroll
        for (int j = 0; j < 8; ++j) v[j] = f2bf(p[j] * Sc[M]);
        wf[M][ks] = v;
      }
  }
  // biases for this lane's 4 output cols, same prescale
  const f32x4 bu4 = (*(const f32x4*)(xu_b + ob) + *(const f32x4*)(hu_b + ob)) * LOG2E;
  const f32x4 br4 = (*(const f32x4*)(xr_b + ob) + *(const f32x4*)(hr_b + ob)) * LOG2E;
  const f32x4 bxg4 = *(const f32x4*)(xg_b + ob) * (2.0f * LOG2E);
  const f32x4 bhg4 = *(const f32x4*)(hg_b + ob) * (2.0f * LOG2E);

  for (int i = tid; i < 16 * 128; i += 512) hbuf[0][i] = 0;

  // ---- fused softmax over T for this block's 16 rows -> att_lds ----
  {
    const int row = tid >> 5, idx = tid & 31;
    const float* srow = att_g + (size_t)(r0 + row) * T_;
    float v[7];
    float mx = -3.0e38f;
#pragma unroll
    for (int i = 0; i < 7; ++i) {
      const int t = idx + i * 32;
      v[i] = (t < T_) ? srow[t] : -3.0e38f;
      mx = fmaxf(mx, v[i]);
    }
#pragma unroll
    for (int d = 1; d < 32; d <<= 1) mx = fmaxf(mx, __shfl_xor(mx, d));
    float sm = 0.0f;
#pragma unroll
    for (int i = 0; i < 7; ++i) {
      v[i] = exp2_f((v[i] - mx) * LOG2E);  // t>=T: exp2(-huge)=0
      sm += v[i];
    }
#pragma unroll
    for (int d = 1; d < 32; d <<= 1) sm += __shfl_xor(sm, d);
    const float rs = rcp_f(sm);
#pragma unroll
    for (int i = 0; i < 7; ++i) {
      const int t = idx + i * 32;
      if (t < T_) att_lds[row * 204 + t] = v[i] * rs;
    }
  }

  // --- x-fragment prefetch state ---
  typedef union { uint4 u; short8 s; } frag_u;
  frag_u xp[2][4];  // xp[f&1] holds x-frags for step f (DIRECT path)
  const short* px = histbf + ((size_t)bb * TSTR * 4) * 512 + (size_t)lane * 8;
  // --- fallback staging state ---
  const int sm_ = tid >> 5, cs = tid & 31;
  const int xpos = sm_ * 128 + (((cs >> 1) ^ (sm_ & 7)) * 8) + (cs & 1) * 4;
  const float* hrow = hist + ((size_t)(r0 + sm_) * T_) * H_ + cs * 4;
  float4 xnext;

  // x-accumulators: xq[t&1] = {xu,xr,xg} partials for step t (bias-seeded).
  f32x4 xq[2][3];

  if constexpr (DIRECT) {
    frag_u x0[4];
#pragma unroll
    for (int ks = 0; ks < 4; ++ks)
      x0[ks].u = *(const uint4*)(px + (size_t)(0 * 4 + ks) * 512);
#pragma unroll
    for (int ks = 0; ks < 4; ++ks)
      xp[1][ks].u = *(const uint4*)(px + (size_t)(1 * 4 + ks) * 512);
#pragma unroll
    for (int ks = 0; ks < 4; ++ks)
      xp[0][ks].u = *(const uint4*)(px + (size_t)(2 * 4 + ks) * 512);
    // xacc(0): first MFMA takes bias as C directly
    xq[0][0] = MFMA(wf[0][0], x0[0].s, bu4);
    xq[0][1] = MFMA(wf[2][0], x0[0].s, br4);
    xq[0][2] = MFMA(wf[4][0], x0[0].s, bxg4);
#pragma unroll
    for (int ks = 1; ks < 4; ++ks) {
      xq[0][0] = MFMA(wf[0][ks], x0[ks].s, xq[0][0]);
      xq[0][1] = MFMA(wf[2][ks], x0[ks].s, xq[0][1]);
      xq[0][2] = MFMA(wf[4][ks], x0[ks].s, xq[0][2]);
    }
  } else {
    float4 a = *(const float4*)hrow;  // x(0)
    uint2 u;
    u.x = pack2bf_rne(a.x, a.y);
    u.y = pack2bf_rne(a.z, a.w);
    *(uint2*)&xbuf[0][xpos] = u;
    xnext = *(const float4*)(hrow + H_);  // x(1)
  }

  // this lane's h state: h[row n][cols ob..ob+3]
  float hreg[4] = {0.0f, 0.0f, 0.0f, 0.0f};
  // h write-back address: 4 consecutive cols inside one swizzle granule
  const int wri = n * 128 + (((w * 2 + (q >> 1)) ^ (n & 7)) * 8) + (q & 1) * 4;
  ck_barrier();  // covers hbuf zero + att_lds + xbuf staging

  // att: one f32x4 per 4 steps from LDS, 2 buffers, 8-step lead
  const float* paL = &att_lds[n * 204];
  f32x4 ab0 = *(const f32x4*)(paL + 0);  // t = 0..3
  f32x4 ab1 = *(const f32x4*)(paL + 4);  // t = 4..7

  if constexpr (DIRECT) {
    const short* pxt = px + (size_t)12 * 512;  // frags for step 3 (t+3 at t=0)
    for (int tb = 0; tb < T_; tb += 8) {       // 200 = 25 * 8
#pragma unroll
      for (int k = 0; k < 8; ++k) {
        const int t = tb + k;
        const int cur = k & 1, nxt = cur ^ 1;
        // h-frags for step t: issue reads first (recurrence-critical)
        short8 ha[4];
#pragma unroll
        for (int ks = 0; ks < 4; ++ks)
          ha[ks] = *(short8*)&hbuf[cur][n * 128 + ((ks * 4 + q) ^ (n & 7)) * 8];

        // x-side for step t+1 FIRST: register-only inputs, no lgkm dep —
        // the 12 MFMAs cover the ds_read(ha) latency after the barrier.
        {
          const short8 x0s = xp[nxt][0].s;
          xq[nxt][0] = MFMA(wf[0][0], x0s, bu4);
          xq[nxt][1] = MFMA(wf[2][0], x0s, br4);
          xq[nxt][2] = MFMA(wf[4][0], x0s, bxg4);
#pragma unroll
          for (int ks = 1; ks < 4; ++ks) {
            const short8 xs = xp[nxt][ks].s;
            xq[nxt][0] = MFMA(wf[0][ks], xs, xq[nxt][0]);
            xq[nxt][1] = MFMA(wf[2][ks], xs, xq[nxt][1]);
            xq[nxt][2] = MFMA(wf[4][ks], xs, xq[nxt][2]);
          }
        }

        // h-side chains C-SEEDED with x-accumulators (u,r) / bias (g)
        f32x4 ahu = MFMA(wf[1][0], ha[0], xq[cur][0]);
        f32x4 ahr = MFMA(wf[3][0], ha[0], xq[cur][1]);
        f32x4 ahg = MFMA(wf[5][0], ha[0], bhg4);
#pragma unroll
        for (int ks = 1; ks < 4; ++ks) {
          ahu = MFMA(wf[1][ks], ha[ks], ahu);
          ahr = MFMA(wf[3][ks], ha[ks], ahr);
          ahg = MFMA(wf[5][ks], ha[ks], ahg);
        }

        // reload slot nxt with frags for step t+3 (pure pointer walk)
#pragma unroll
        for (int ks = 0; ks < 4; ++ks)
          xp[nxt][ks].u = *(const uint4*)(pxt + (size_t)(k * 4 + ks) * 512);

        // att for this step (masks fold; reloads from LDS, aligned)
        const float at = ((k >> 2) & 1) ? ab1[k & 3] : ab0[k & 3];
        if (k == 3) ab0 = *(const f32x4*)(paL + ((t + 5 <= T_ - 4) ? t + 5 : T_ - 4));
        if (k == 7) ab1 = *(const f32x4*)(paL + ((t + 5 <= T_ - 4) ? t + 5 : T_ - 4));

        // gates: pre-activations complete and exp2-prescaled
        float hn[4];
#pragma unroll
        for (int r = 0; r < 4; ++r) {
          const float uu = at * rcp_f(1.0f + exp2_f(-ahu[r]));
          const float rr = rcp_f(1.0f + exp2_f(-ahr[r]));
          const float sg = xq[cur][2][r] + rr * ahg[r];
          const float g = 2.0f * rcp_f(1.0f + exp2_f(-sg)) - 1.0f;
          hn[r] = hreg[r] + uu * (g - hreg[r]);
          hreg[r] = hn[r];
        }

        // single 8B LDS write: 4 consecutive bf16 cols of row n (v_perm packs)
        uint2 up;
        up.x = pack2bf_trunc(hn[0], hn[1]);
        up.y = pack2bf_trunc(hn[2], hn[3]);
        *(uint2*)&hbuf[nxt][wri] = up;
        ck_barrier();
      }
      pxt += (size_t)8 * 4 * 512;
    }
  } else {
    // fallback: LDS-staged x path
#pragma unroll 2
    for (int t = 0; t < T_; ++t) {
      const int cur = t & 1, nxt = cur ^ 1;
      short8 ha[4];
#pragma unroll
      for (int ks = 0; ks < 4; ++ks)
        ha[ks] = *(short8*)&hbuf[cur][n * 128 + ((ks * 4 + q) ^ (n & 7)) * 8];
      short8 xa[4];
#pragma unroll
      for (int ks = 0; ks < 4; ++ks)
        xa[ks] = *(short8*)&xbuf[cur][n * 128 + ((ks * 4 + q) ^ (n & 7)) * 8];
      f32x4 xu_a = MFMA(wf[0][0], xa[0], bu4);
      f32x4 xr_a = MFMA(wf[2][0], xa[0], br4);
      f32x4 xg_a = MFMA(wf[4][0], xa[0], bxg4);
#pragma unroll
      for (int ks = 1; ks < 4; ++ks) {
        xu_a = MFMA(wf[0][ks], xa[ks], xu_a);
        xr_a = MFMA(wf[2][ks], xa[ks], xr_a);
        xg_a = MFMA(wf[4][ks], xa[ks], xg_a);
      }
      f32x4 ahu = MFMA(wf[1][0], ha[0], xu_a);
      f32x4 ahr = MFMA(wf[3][0], ha[0], xr_a);
      f32x4 ahg = MFMA(wf[5][0], ha[0], bhg4);
#pragma unroll
      for (int ks = 1; ks < 4; ++ks) {
        ahu = MFMA(wf[1][ks], ha[ks], ahu);
        ahr = MFMA(wf[3][ks], ha[ks], ahr);
        ahg = MFMA(wf[5][ks], ha[ks], ahg);
      }
      const int tp = (t + 2 < T_) ? t + 2 : T_ - 1;
      const float at = ((t >> 2) & 1) ? ab1[t & 3] : ab0[t & 3];
      if ((t & 7) == 3) ab0 = *(const f32x4*)(paL + ((t + 5 <= T_ - 4) ? t + 5 : T_ - 4));
      if ((t & 7) == 7) ab1 = *(const f32x4*)(paL + ((t + 5 <= T_ - 4) ? t + 5 : T_ - 4));
      float hn[4];
#pragma unroll
      for (int r = 0; r < 4; ++r) {
        const float uu = at * rcp_f(1.0f + exp2_f(-ahu[r]));
        const float rr = rcp_f(1.0f + exp2_f(-ahr[r]));
        const float sg = xg_a[r] + rr * ahg[r];
        const float g = 2.0f * rcp_f(1.0f + exp2_f(-sg)) - 1.0f;
        hn[r] = hreg[r] + uu * (g - hreg[r]);
        hreg[r] = hn[r];
      }
      uint2 up;
      up.x = pack2bf_trunc(hn[0], hn[1]);
      up.y = pack2bf_trunc(hn[2], hn[3]);
      *(uint2*)&hbuf[nxt][wri] = up;
      uint2 u;
      u.x = pack2bf_rne(xnext.x, xnext.y);
      u.y = pack2bf_rne(xnext.z, xnext.w);
      *(uint2*)&xbuf[nxt][xpos] = u;  // stage x(t+1)
      xnext = *(const float4*)(hrow + (size_t)tp * H_);
      ck_barrier();
    }
  }

  // ---- fused final layer: out = [h | tgt0] @ ln2_w^T + ln2_b (fp32) ----
  // h(T-1) fp32 -> LDS (att_lds reused; all att reads are done). Stride 132.
  {
    f32x4 hv4 = {hreg[0], hreg[1], hreg[2], hreg[3]};
    *(f32x4*)&att_lds[n * 132 + ob] = hv4;
    ck_barrier();
    const int row = tid & 15, og = tid >> 4;  // og in 0..31, 4 outputs each
    const float* wb_ = ln2_w + (size_t)(og * 4) * 256;
    const float* trow = tgt + (size_t)(r0 + row) * (T_ * H_);
    f32x4 acc = *(const f32x4*)(ln2_b + og * 4);
#pragma unroll 4
    for (int k = 0; k < 128; k += 4) {
      const f32x4 h4 = *(const f32x4*)&att_lds[row * 132 + k];
      const float4 t4 = *(const float4*)(trow + k);
#pragma unroll
      for (int j = 0; j < 4; ++j) {
        const float4 w0 = *(const float4*)(wb_ + j * 256 + k);
        const float4 w1 = *(const float4*)(wb_ + j * 256 + 128 + k);
        acc[j] += h4[0] * w0.x + h4[1] * w0.y + h4[2] * w0.z + h4[3] * w0.w +
                  t4.x * w1.x + t4.y * w1.y + t4.z * w1.z + t4.w * w1.w;
      }
    }
    float4 ov = {acc[0], acc[1], acc[2], acc[3]};
    *(float4*)(out + (size_t)(r0 + row) * H_ + og * 4) = ov;
  }
}

extern "C" void kernel_launch(void* const* d_in, const int* in_sizes, int n_in,
                              void* d_out, int out_size, void* d_ws, size_t ws_size,
                              hipStream_t stream) {
  const float* targets = (const float*)d_in[0];
  const float* history = (const float*)d_in[1];
  const float* W_w = (const float*)d_in[2];
  const float* W_b = (const float*)d_in[3];
  const float* xu_w = (const float*)d_in[4];
  const float* xu_b = (const float*)d_in[5];
  const float* hu_w = (const float*)d_in[6];
  const float* hu_b = (const float*)d_in[7];
  const float* xr_w = (const float*)d_in[8];
  const float* xr_b = (const float*)d_in[9];
  const float* hr_w = (const float*)d_in[10];
  const float* hr_b = (const float*)d_in[11];
  const float* xg_w = (const float*)d_in[12];
  const float* xg_b = (const float*)d_in[13];
  const float* hg_w = (const float*)d_in[14];
  const float* hg_b = (const float*)d_in[15];
  const float* ln2_w = (const float*)d_in[16];
  const float* ln2_b = (const float*)d_in[17];
  float* out = (float*)d_out;

  float* att = (float*)d_ws;  // [B,T] f32 (raw scores; softmax fused in scan)
  const size_t fixed = (size_t)B_ * T_ * 4 + (size_t)B_ * H_ * 4;
  const size_t histbf_bytes = (size_t)64 * TSTR * 4 * 512 * 2;  // 53.5 MB
  short* histbf = (ws_size >= fixed + histbf_bytes)
                      ? (short*)((char*)d_ws + fixed)
                      : nullptr;

  proj_scores_kernel<<<dim3(13, 64), dim3(512), 0, stream>>>(
      targets, history, W_w, W_b, att, histbf);
  if (histbf) {
    scan3_kernel<true><<<dim3(64), dim3(512), 0, stream>>>(
        history, targets, xu_w, xu_b, hu_w, hu_b, xr_w, xr_b, hr_w, hr_b,
        xg_w, xg_b, hg_w, hg_b, att, histbf, ln2_w, ln2_b, out);
  } else {
    scan3_kernel<false><<<dim3(64), dim3(512), 0, stream>>>(
        history, targets, xu_w, xu_b, hu_w, hu_b, xr_w, xr_b, hr_w, hr_b,
        xg_w, xg_b, hg_w, hg_b, att, histbf, ln2_w, ln2_b, out);
  }
}